// Round 11
// baseline (269.930 us; speedup 1.0000x reference)
//
#include <hip/hip_runtime.h>
#include <hip/hip_fp16.h>

// MessagePassing: 10 iterations of 3x3 per-pixel-weighted smoothing.
//   input [8,64,128,128] f32, weight [8,9,128,128] f32 -> out [8,64,128,128] f32
// R11: occupancy attack. R10 was latency/barrier-bound (LDS 46%, VALU ~30%,
// 1 block/CU = 3.25 waves/SIMD). Now: 512 blocks = 2/CU, 26 waves/CU.
//  - x-cells 1px x 4ch fp16 (uint2): two ping-pong buffers = 53.2 KB/block.
//  - NO weight LDS: per-step ds-free weight reads from a zero-padded global
//    fp16 table [n][9][144][32] (pads -> OOB rows are weight-0, no branches;
//    each XCD serves one image's 0.3 MB weights from its L2 via n=bid&7).
//  - 64-VGPR tier required for 26 waves/CU: loop live ~50 regs, lb(832,7).

#define NB    8
#define CC    64
#define HH    128
#define WW    128
#define TAPS  9
#define PLANE (HH * WW)

#define CORE   16            // output tile rows per kernel
#define HALO5  5
#define RROWS  26            // CORE + 2*HALO5
#define CSTR   128           // x-buffer row stride in uint2 cells
#define NTH    832           // 26 rows * 32 strips, 13 waves
#define NSTEP  5
#define CGRP   8             // channels per block
#define CSUB   4             // channels per chunk (fp16 x4 in uint2 cell)
#define WPAD   8             // zero pad rows above/below in weight table
#define WH     144           // 128 + 2*WPAD padded weight rows
#define WROWSTR 32           // uint2 cells per weight row

#define PERM4(J) ((((J) & 3) << 5) | ((J) >> 2))   // bijective on 0..127

#define NWCELLS ((size_t)NB * TAPS * WH * WROWSTR)   // uint2 cells (2.65 MB)

__device__ __forceinline__ float4 fma4(const float4 a, const float s, const float4 c) {
    return make_float4(fmaf(a.x, s, c.x), fmaf(a.y, s, c.y),
                       fmaf(a.z, s, c.z), fmaf(a.w, s, c.w));
}
__device__ __forceinline__ unsigned pack2(float a, float b) {
    __half2 h = __floats2half2_rn(a, b);
    return *reinterpret_cast<unsigned*>(&h);
}
__device__ __forceinline__ float2 h22f2(unsigned u) {
    return __half22float2(*reinterpret_cast<const __half2*>(&u));
}
__device__ __forceinline__ float4 cvt4(const uint2 v) {
    const float2 a = h22f2(v.x);
    const float2 b = h22f2(v.y);
    return make_float4(a.x, a.y, b.x, b.y);
}

// Normalize taps -> fp16 padded table [n][9][144][32] uint2 (half4 = 4 px).
// Rows 0..7 and 136..143 are zero pads (so OOB-image rows get 0 weights).
__global__ __launch_bounds__(256) void mp_norm_kernel(const float* __restrict__ w,
                                                      uint2* __restrict__ nwp) {
    int tid = blockIdx.x * 256 + threadIdx.x;       // 32768 threads
    int wg = tid & 31;
    int h  = (tid >> 5) & 127;
    int n  = tid >> 12;
    int base = n * TAPS * PLANE + h * WW + wg * 4;
    float4 t[TAPS];
    float sx = 1e-5f, sy = 1e-5f, sz = 1e-5f, sw = 1e-5f;
#pragma unroll
    for (int k = 0; k < TAPS; ++k) {
        t[k] = *reinterpret_cast<const float4*>(w + base + k * PLANE);
        sx += t[k].x; sy += t[k].y; sz += t[k].z; sw += t[k].w;
    }
    float rx = 1.0f / sx, ry = 1.0f / sy, rz = 1.0f / sz, rw = 1.0f / sw;
#pragma unroll
    for (int k = 0; k < TAPS; ++k) {
        uint2 v;
        v.x = pack2(t[k].x * rx, t[k].y * ry);
        v.y = pack2(t[k].z * rz, t[k].w * rw);
        nwp[(((size_t)n * TAPS + k) * WH + (h + WPAD)) * WROWSTR + wg] = v;
    }
    // zero pads: threads with h<8 clear top row h and bottom row 136+h
    if (h < WPAD) {
        const uint2 zc = make_uint2(0u, 0u);
#pragma unroll
        for (int k = 0; k < TAPS; ++k) {
            nwp[(((size_t)n * TAPS + k) * WH + h) * WROWSTR + wg] = zc;
            nwp[(((size_t)n * TAPS + k) * WH + (WPAD + HH + h)) * WROWSTR + wg] = zc;
        }
    }
}

__global__ __launch_bounds__(NTH, 7) void mp_fused5_kernel(const float* __restrict__ src,
                                                           float* __restrict__ dst,
                                                           const uint2* __restrict__ nwp) {
    __shared__ uint2 bufA[RROWS * CSTR];     // 26,624 B
    __shared__ uint2 bufB[RROWS * CSTR];     // total 53,248 B -> 2 blocks/CU

    const int bid = blockIdx.x;              // 512 blocks
    const int n   = bid & 7;                 // image -> XCD affinity (weights L2-local)
    const int ht  = (bid >> 3) & 7;
    const int cg  = bid >> 6;                // 0..7
    const int tr0 = ht * CORE;
    const int cb  = cg * CGRP;

    const int t   = threadIdx.x;
    const int row = t >> 5;                  // 0..25 region row
    const int s   = t & 31;                  // strip: pixels 4s..4s+3

    const int gr = tr0 - HALO5 + row;        // thread's global image row
    // weight base: tap k at + k*WH*32 cells; padded rows make OOB -> 0
    const uint2* wbase = nwp + ((size_t)n * TAPS * WH + (gr + WPAD)) * WROWSTR + s;

    const uint2 zc = make_uint2(0u, 0u);
    const float4 z = make_float4(0.f, 0.f, 0.f, 0.f);

    for (int ch = 0; ch < CGRP; ch += CSUB) {            // 2 chunks
        const float* sp = src + ((size_t)n * CC + cb + ch) * PLANE;

        // ---- load 26x128 region x 4 channels -> fp16 cells (zero-pad rows) ----
        for (int idx = t; idx < RROWS * WW; idx += NTH) {    // exactly 4 iters
            const int r  = idx >> 7;
            const int J  = idx & 127;
            const int g  = tr0 - HALO5 + r;
            uint2 v = zc;
            if (g >= 0 && g < HH) {
                const int o = g * WW + J;
                v.x = pack2(sp[o],             sp[PLANE + o]);
                v.y = pack2(sp[2 * PLANE + o], sp[3 * PLANE + o]);
            }
            bufA[r * CSTR + PERM4(J)] = v;
        }
        __syncthreads();

        // ---- 5 fused steps, valid rows shrink top/bottom by 1 per step ----
        uint2* pin  = bufA;
        uint2* pout = bufB;
        for (int st = 0; st < NSTEP; ++st) {
            const int lo = st + 1;
            const int hi = 24 - st;
            if (row >= lo && row <= hi) {
                // defeat LICM of the 9 per-step weight loads (hoisting them
                // across the st-loop = 18 regs held forever = spill trap)
                int wo = 0;
                asm volatile("" : "+v"(wo));
                float4 a0 = z, a1 = z, a2 = z, a3 = z;
#pragma unroll
                for (int di = 0; di < 3; ++di) {
                    // 3 weight taps for this di (global, coalesced, L2-hot)
                    const uint2 wv0 = wbase[wo + (di * 3 + 0) * (WH * WROWSTR)];
                    const uint2 wv1 = wbase[wo + (di * 3 + 1) * (WH * WROWSTR)];
                    const uint2 wv2 = wbase[wo + (di * 3 + 2) * (WH * WROWSTR)];
                    const uint2* rp = pin + (row - 1 + di) * CSTR;
                    float4 xc[6];
                    xc[0] = (s > 0) ? cvt4(rp[96 + s - 1]) : z;  // col 4s-1
                    xc[1] = cvt4(rp[s]);                         // col 4s
                    xc[2] = cvt4(rp[32 + s]);                    // col 4s+1
                    xc[3] = cvt4(rp[64 + s]);                    // col 4s+2
                    xc[4] = cvt4(rp[96 + s]);                    // col 4s+3
                    xc[5] = (s < 31) ? cvt4(rp[s + 1]) : z;      // col 4s+4
                    {
                        const float2 w01 = h22f2(wv0.x), w23 = h22f2(wv0.y);
                        a0 = fma4(xc[0], w01.x, a0);
                        a1 = fma4(xc[1], w01.y, a1);
                        a2 = fma4(xc[2], w23.x, a2);
                        a3 = fma4(xc[3], w23.y, a3);
                    }
                    {
                        const float2 w01 = h22f2(wv1.x), w23 = h22f2(wv1.y);
                        a0 = fma4(xc[1], w01.x, a0);
                        a1 = fma4(xc[2], w01.y, a1);
                        a2 = fma4(xc[3], w23.x, a2);
                        a3 = fma4(xc[4], w23.y, a3);
                    }
                    {
                        const float2 w01 = h22f2(wv2.x), w23 = h22f2(wv2.y);
                        a0 = fma4(xc[2], w01.x, a0);
                        a1 = fma4(xc[3], w01.y, a1);
                        a2 = fma4(xc[4], w23.x, a2);
                        a3 = fma4(xc[5], w23.y, a3);
                    }
                }
                uint2* op = pout + row * CSTR;
                op[s]      = make_uint2(pack2(a0.x, a0.y), pack2(a0.z, a0.w));
                op[32 + s] = make_uint2(pack2(a1.x, a1.y), pack2(a1.z, a1.w));
                op[64 + s] = make_uint2(pack2(a2.x, a2.y), pack2(a2.z, a2.w));
                op[96 + s] = make_uint2(pack2(a3.x, a3.y), pack2(a3.z, a3.w));
            }
            __syncthreads();
            uint2* tmp = pin; pin = pout; pout = tmp;
        }

        // ---- store 16x128 core x 4 channels ----
        float* dp = dst + ((size_t)n * CC + cb + ch) * PLANE;
        for (int idx = t; idx < CORE * WW; idx += NTH) {
            const int r = idx >> 7;
            const int J = idx & 127;
            const uint2 v = pin[(r + HALO5) * CSTR + PERM4(J)];
            const float2 c01 = h22f2(v.x);
            const float2 c23 = h22f2(v.y);
            const int o = (tr0 + r) * WW + J;
            dp[o]             = c01.x;
            dp[PLANE + o]     = c01.y;
            dp[2 * PLANE + o] = c23.x;
            dp[3 * PLANE + o] = c23.y;
        }
        __syncthreads();   // protect bufA before next chunk's load
    }
}

extern "C" void kernel_launch(void* const* d_in, const int* in_sizes, int n_in,
                              void* d_out, int out_size, void* d_ws, size_t ws_size,
                              hipStream_t stream) {
    const float* input  = (const float*)d_in[0];
    const float* weight = (const float*)d_in[1];
    float* out = (float*)d_out;

    uint2* nwp = (uint2*)d_ws;                               // 2.65 MB padded fp16 weights
    float* B0  = (float*)((char*)d_ws + NWCELLS * sizeof(uint2));  // 33.5 MB intermediate

    mp_norm_kernel<<<128, 256, 0, stream>>>(weight, nwp);
    mp_fused5_kernel<<<512, NTH, 0, stream>>>(input, B0, nwp);  // steps 1..5
    mp_fused5_kernel<<<512, NTH, 0, stream>>>(B0, out, nwp);    // steps 6..10
}

// Round 12
// 99.553 us; speedup vs baseline: 2.7114x; 2.7114x over previous
//
#include <hip/hip_runtime.h>
#include <hip/hip_fp16.h>

// MessagePassing: 10 iterations of 3x3 per-pixel-weighted smoothing.
//   input [8,64,128,128] f32, weight [8,9,128,128] f32 -> out [8,64,128,128] f32
// R12 = R11 (2-blocks/CU design: 512 blocks, 4ch fp16 x-cells, 53KB LDS,
// weights from zero-padded global fp16 table, XCD-local) with two fixes:
//  - __launch_bounds__(NTH, 1): R11's (NTH,7) made the backend target a
//    36-VGPR tier and spill accumulators to scratch (WRITE 318MB). Loop live
//    set ~60 regs; any VGPR<=72 still allows 26 waves/CU. Let it choose.
//  - intermediate B0 stored as raw fp16 uint2 cells [n][c/4][h][w]: store and
//    reload are plain uint2 copies (no cvt/pack), bit-identical math, halves
//    intermediate traffic.

#define NB    8
#define CC    64
#define HH    128
#define WW    128
#define TAPS  9
#define PLANE (HH * WW)

#define CORE   16            // output tile rows per kernel
#define HALO5  5
#define RROWS  26            // CORE + 2*HALO5
#define CSTR   128           // x-buffer row stride in uint2 cells
#define NTH    832           // 26 rows * 32 strips, 13 waves
#define NSTEP  5
#define CGRP   8             // channels per block
#define CSUB   4             // channels per chunk (fp16 x4 in uint2 cell)
#define WPAD   8             // zero pad rows above/below in weight table
#define WH     144           // 128 + 2*WPAD padded weight rows
#define WROWSTR 32           // uint2 cells per weight row

#define PERM4(J) ((((J) & 3) << 5) | ((J) >> 2))   // bijective on 0..127

#define NWCELLS ((size_t)NB * TAPS * WH * WROWSTR)   // uint2 cells (2.65 MB)

__device__ __forceinline__ float4 fma4(const float4 a, const float s, const float4 c) {
    return make_float4(fmaf(a.x, s, c.x), fmaf(a.y, s, c.y),
                       fmaf(a.z, s, c.z), fmaf(a.w, s, c.w));
}
__device__ __forceinline__ unsigned pack2(float a, float b) {
    __half2 h = __floats2half2_rn(a, b);
    return *reinterpret_cast<unsigned*>(&h);
}
__device__ __forceinline__ float2 h22f2(unsigned u) {
    return __half22float2(*reinterpret_cast<const __half2*>(&u));
}
__device__ __forceinline__ float4 cvt4(const uint2 v) {
    const float2 a = h22f2(v.x);
    const float2 b = h22f2(v.y);
    return make_float4(a.x, a.y, b.x, b.y);
}

// Normalize taps -> fp16 padded table [n][9][144][32] uint2 (half4 = 4 px).
// Rows 0..7 and 136..143 are zero pads (so OOB-image rows get 0 weights).
__global__ __launch_bounds__(256) void mp_norm_kernel(const float* __restrict__ w,
                                                      uint2* __restrict__ nwp) {
    int tid = blockIdx.x * 256 + threadIdx.x;       // 32768 threads
    int wg = tid & 31;
    int h  = (tid >> 5) & 127;
    int n  = tid >> 12;
    int base = n * TAPS * PLANE + h * WW + wg * 4;
    float4 t[TAPS];
    float sx = 1e-5f, sy = 1e-5f, sz = 1e-5f, sw = 1e-5f;
#pragma unroll
    for (int k = 0; k < TAPS; ++k) {
        t[k] = *reinterpret_cast<const float4*>(w + base + k * PLANE);
        sx += t[k].x; sy += t[k].y; sz += t[k].z; sw += t[k].w;
    }
    float rx = 1.0f / sx, ry = 1.0f / sy, rz = 1.0f / sz, rw = 1.0f / sw;
#pragma unroll
    for (int k = 0; k < TAPS; ++k) {
        uint2 v;
        v.x = pack2(t[k].x * rx, t[k].y * ry);
        v.y = pack2(t[k].z * rz, t[k].w * rw);
        nwp[(((size_t)n * TAPS + k) * WH + (h + WPAD)) * WROWSTR + wg] = v;
    }
    if (h < WPAD) {
        const uint2 zc = make_uint2(0u, 0u);
#pragma unroll
        for (int k = 0; k < TAPS; ++k) {
            nwp[(((size_t)n * TAPS + k) * WH + h) * WROWSTR + wg] = zc;
            nwp[(((size_t)n * TAPS + k) * WH + (WPAD + HH + h)) * WROWSTR + wg] = zc;
        }
    }
}

// SRC_F32: src is f32 [n][64][128][128]; else fp16 uint2 cells [n][16][128][128].
// DST_F32: dst is f32 [n][64][128][128]; else fp16 uint2 cells.
template <bool SRC_F32, bool DST_F32>
__global__ __launch_bounds__(NTH, 1) void mp_fused5_kernel(const void* __restrict__ srcv,
                                                           void* __restrict__ dstv,
                                                           const uint2* __restrict__ nwp) {
    __shared__ uint2 bufA[RROWS * CSTR];     // 26,624 B
    __shared__ uint2 bufB[RROWS * CSTR];     // total 53,248 B -> 2 blocks/CU

    const int bid = blockIdx.x;              // 512 blocks
    const int n   = bid & 7;                 // image -> XCD affinity (weights L2-local)
    const int ht  = (bid >> 3) & 7;
    const int cg  = bid >> 6;                // 0..7
    const int tr0 = ht * CORE;
    const int cb  = cg * CGRP;

    const int t   = threadIdx.x;
    const int row = t >> 5;                  // 0..25 region row
    const int s   = t & 31;                  // strip: pixels 4s..4s+3

    const int gr = tr0 - HALO5 + row;        // thread's global image row
    const uint2* wbase = nwp + ((size_t)n * TAPS * WH + (gr + WPAD)) * WROWSTR + s;

    const uint2 zc = make_uint2(0u, 0u);
    const float4 z = make_float4(0.f, 0.f, 0.f, 0.f);

    for (int ch = 0; ch < CGRP; ch += CSUB) {            // 2 chunks
        const int ci4 = (cb + ch) >> 2;                  // channel-quad index

        // ---- load 26x128 region x 4 channels -> fp16 cells (zero-pad rows) ----
        for (int idx = t; idx < RROWS * WW; idx += NTH) {    // exactly 4 iters
            const int r  = idx >> 7;
            const int J  = idx & 127;
            const int g  = tr0 - HALO5 + r;
            uint2 v = zc;
            if (g >= 0 && g < HH) {
                if (SRC_F32) {
                    const float* sp = (const float*)srcv + ((size_t)n * CC + cb + ch) * PLANE;
                    const int o = g * WW + J;
                    v.x = pack2(sp[o],             sp[PLANE + o]);
                    v.y = pack2(sp[2 * PLANE + o], sp[3 * PLANE + o]);
                } else {
                    const uint2* sp16 = (const uint2*)srcv + ((size_t)n * (CC / 4) + ci4) * PLANE;
                    v = sp16[g * WW + J];
                }
            }
            bufA[r * CSTR + PERM4(J)] = v;
        }
        __syncthreads();

        // ---- 5 fused steps, valid rows shrink top/bottom by 1 per step ----
        uint2* pin  = bufA;
        uint2* pout = bufB;
        for (int st = 0; st < NSTEP; ++st) {
            const int lo = st + 1;
            const int hi = 24 - st;
            if (row >= lo && row <= hi) {
                int wo = 0;
                asm volatile("" : "+v"(wo));             // keep weight reads in-loop
                float4 a0 = z, a1 = z, a2 = z, a3 = z;
#pragma unroll
                for (int di = 0; di < 3; ++di) {
                    const uint2 wv0 = wbase[wo + (di * 3 + 0) * (WH * WROWSTR)];
                    const uint2 wv1 = wbase[wo + (di * 3 + 1) * (WH * WROWSTR)];
                    const uint2 wv2 = wbase[wo + (di * 3 + 2) * (WH * WROWSTR)];
                    const uint2* rp = pin + (row - 1 + di) * CSTR;
                    float4 xc[6];
                    xc[0] = (s > 0) ? cvt4(rp[96 + s - 1]) : z;  // col 4s-1
                    xc[1] = cvt4(rp[s]);                         // col 4s
                    xc[2] = cvt4(rp[32 + s]);                    // col 4s+1
                    xc[3] = cvt4(rp[64 + s]);                    // col 4s+2
                    xc[4] = cvt4(rp[96 + s]);                    // col 4s+3
                    xc[5] = (s < 31) ? cvt4(rp[s + 1]) : z;      // col 4s+4
                    {
                        const float2 w01 = h22f2(wv0.x), w23 = h22f2(wv0.y);
                        a0 = fma4(xc[0], w01.x, a0);
                        a1 = fma4(xc[1], w01.y, a1);
                        a2 = fma4(xc[2], w23.x, a2);
                        a3 = fma4(xc[3], w23.y, a3);
                    }
                    {
                        const float2 w01 = h22f2(wv1.x), w23 = h22f2(wv1.y);
                        a0 = fma4(xc[1], w01.x, a0);
                        a1 = fma4(xc[2], w01.y, a1);
                        a2 = fma4(xc[3], w23.x, a2);
                        a3 = fma4(xc[4], w23.y, a3);
                    }
                    {
                        const float2 w01 = h22f2(wv2.x), w23 = h22f2(wv2.y);
                        a0 = fma4(xc[2], w01.x, a0);
                        a1 = fma4(xc[3], w01.y, a1);
                        a2 = fma4(xc[4], w23.x, a2);
                        a3 = fma4(xc[5], w23.y, a3);
                    }
                }
                uint2* op = pout + row * CSTR;
                op[s]      = make_uint2(pack2(a0.x, a0.y), pack2(a0.z, a0.w));
                op[32 + s] = make_uint2(pack2(a1.x, a1.y), pack2(a1.z, a1.w));
                op[64 + s] = make_uint2(pack2(a2.x, a2.y), pack2(a2.z, a2.w));
                op[96 + s] = make_uint2(pack2(a3.x, a3.y), pack2(a3.z, a3.w));
            }
            __syncthreads();
            uint2* tmp = pin; pin = pout; pout = tmp;
        }

        // ---- store 16x128 core x 4 channels ----
        for (int idx = t; idx < CORE * WW; idx += NTH) {
            const int r = idx >> 7;
            const int J = idx & 127;
            const uint2 v = pin[(r + HALO5) * CSTR + PERM4(J)];
            if (DST_F32) {
                float* dp = (float*)dstv + ((size_t)n * CC + cb + ch) * PLANE;
                const float2 c01 = h22f2(v.x);
                const float2 c23 = h22f2(v.y);
                const int o = (tr0 + r) * WW + J;
                dp[o]             = c01.x;
                dp[PLANE + o]     = c01.y;
                dp[2 * PLANE + o] = c23.x;
                dp[3 * PLANE + o] = c23.y;
            } else {
                uint2* dp16 = (uint2*)dstv + ((size_t)n * (CC / 4) + ci4) * PLANE;
                dp16[(tr0 + r) * WW + J] = v;                   // raw fp16 cells
            }
        }
        __syncthreads();   // protect bufA before next chunk's load
    }
}

extern "C" void kernel_launch(void* const* d_in, const int* in_sizes, int n_in,
                              void* d_out, int out_size, void* d_ws, size_t ws_size,
                              hipStream_t stream) {
    const float* input  = (const float*)d_in[0];
    const float* weight = (const float*)d_in[1];
    float* out = (float*)d_out;

    uint2* nwp = (uint2*)d_ws;                               // 2.65 MB padded fp16 weights
    uint2* B0  = (uint2*)((char*)d_ws + NWCELLS * sizeof(uint2));  // 16.8 MB fp16 cells

    mp_norm_kernel<<<128, 256, 0, stream>>>(weight, nwp);
    mp_fused5_kernel<true, false><<<512, NTH, 0, stream>>>(input, B0, nwp);  // steps 1..5
    mp_fused5_kernel<false, true><<<512, NTH, 0, stream>>>(B0, out, nwp);    // steps 6..10
}